// Round 5
// baseline (1197.885 us; speedup 1.0000x reference)
//
#include <hip/hip_runtime.h>
#include <hip/hip_bf16.h>
#include <cmath>

#define E_EDGES 800000
#define N_NODES 50000
#define BN_EPS 1e-5f

typedef __attribute__((ext_vector_type(8))) short short8;
typedef __attribute__((ext_vector_type(4))) float float4v;
typedef unsigned short ushort_t;
typedef unsigned long long ull_t;

#define MFMA16(a, b, c) __builtin_amdgcn_mfma_f32_16x16x32_bf16((a), (b), (c), 0, 0, 0)

// ---- workspace layout (float offsets) ----
#define OFF_GX 0                               // Gram(x) [48][48] (row 34 = ones)
#define OFF_GH 2304                            // Gram(h) [144][144] (row 128 = ones)
#define OFF_A1 23040
#define OFF_C1 23168
#define OFF_A2 23296
#define OFF_C2 23552
#define OFF_GS2SUM 23936
#define OFF_GS2SQ 24000
#define OFF_FS1SUM 24064
#define OFF_FS1SQ 24192
#define OFF_FS2SUM 24320
#define OFF_FS2SQ 24448
#define OFF_GG 24576                           // Gram(geom) [64][64] (row 48 = ones)
#define OFF_GA1 28672
#define OFF_GC1 28736
#define OFF_NODE 28800                         // node_acc [N,128]
#define OFF_TG2 (OFF_NODE + N_NODES * 128)     // tg2 [N,64]
#define OFF_TF1 (OFF_TG2 + N_NODES * 64)       // tf1 [N,128]; sort arrays live here pre-fuse1
#define OFF_TF2 OFF_NODE                       // tf2 reuses node_acc (dead after fuse1)
#define OFF_W1T (OFF_TF1 + N_NODES * 128)      // w1T bf16 [128][64]
#define OFF_W2T (OFF_W1T + 4096)               // w2T bf16 [256][128]
#define OFF_WF1T (OFF_W2T + 16384)             // wf1T bf16 [128][192]
#define OFF_WF2T (OFF_WF1T + 12288)            // wf2T bf16 [128][128]

// sort arrays: int offsets relative to (int*)(ws + OFF_TF1)
#define OFFI_CNT 0        // [50048]
#define OFFI_CUR 50048    // [50048]
#define OFFI_PERM 100096  // [800000]
#define OFFI_SVID 900096  // [800000]

__device__ __forceinline__ float frcp_(float x) { return __builtin_amdgcn_rcpf(x); }
__device__ __forceinline__ float sigmoid_(float x) { return frcp_(1.0f + __expf(-x)); }
__device__ __forceinline__ float softplus_(float x) {
  return (x > 20.0f) ? x : __logf(1.0f + __expf(x));
}
__device__ __forceinline__ float silu_(float x) { return x * frcp_(1.0f + __expf(-x)); }

__device__ __forceinline__ ushort_t f2bf(float f) {
  __hip_bfloat16 h = __float2bfloat16(f);
  return *(ushort_t*)&h;
}
__device__ __forceinline__ float bf2f(ushort_t u) {
  return __uint_as_float(((unsigned)u) << 16);
}
__device__ __forceinline__ ull_t pack4(float a, float b, float c, float d) {
  return (ull_t)f2bf(a) | ((ull_t)f2bf(b) << 16) | ((ull_t)f2bf(c) << 32) |
         ((ull_t)f2bf(d) << 48);
}

// x A-frag for MFMA 16x16x32: lane holds x[e][8qd..8qd+7] (ks=0) and x[e][32..33] pad (ks=1)
__device__ __forceinline__ void load_xfrag(const float* __restrict__ chem, int e, int qd,
                                           short8* x0, short8* x1) {
  const float* xe = chem + e * 34;
  float2 p0 = *(const float2*)(xe + 8 * qd);
  float2 p1 = *(const float2*)(xe + 8 * qd + 2);
  float2 p2 = *(const float2*)(xe + 8 * qd + 4);
  float2 p3 = *(const float2*)(xe + 8 * qd + 6);
  short8 a;
  a[0] = (short)f2bf(p0.x); a[1] = (short)f2bf(p0.y);
  a[2] = (short)f2bf(p1.x); a[3] = (short)f2bf(p1.y);
  a[4] = (short)f2bf(p2.x); a[5] = (short)f2bf(p2.y);
  a[6] = (short)f2bf(p3.x); a[7] = (short)f2bf(p3.y);
  *x0 = a;
  short8 b = (short8){0, 0, 0, 0, 0, 0, 0, 0};
  if (qd == 0) {
    float2 pt = *(const float2*)(xe + 32);
    b[0] = (short)f2bf(pt.x); b[1] = (short)f2bf(pt.y);
  }
  *x1 = b;
}

// ---------------- prep: transpose+convert weights to bf16 in ws ----------------
__global__ __launch_bounds__(256) void k_prep(const float* __restrict__ w1,
                                              const float* __restrict__ w2,
                                              const float* __restrict__ wf1,
                                              const float* __restrict__ wf2,
                                              float* __restrict__ ws) {
  int idx = blockIdx.x * 256 + threadIdx.x;
  if (idx < 8192) {  // w1T[c][k], c=idx>>6, k padded 34->64
    int c = idx >> 6, k = idx & 63;
    ((ushort_t*)(ws + OFF_W1T))[idx] = f2bf((k < 34) ? w1[k * 128 + c] : 0.0f);
  } else if (idx < 40960) {  // w2T[c][k]
    int j = idx - 8192;
    ((ushort_t*)(ws + OFF_W2T))[j] = f2bf(w2[(j & 127) * 256 + (j >> 7)]);
  } else if (idx < 65536) {  // wf1T[c][k], k<192
    int j = idx - 40960;
    int c = j / 192, k = j - c * 192;
    ((ushort_t*)(ws + OFF_WF1T))[j] = f2bf(wf1[k * 128 + c]);
  } else if (idx < 81920) {  // wf2T[c][k]
    int j = idx - 65536;
    ((ushort_t*)(ws + OFF_WF2T))[j] = f2bf(wf2[(j & 127) * 128 + (j >> 7)]);
  }
}

// ---------------- counting sort of edges by vid ----------------
__global__ __launch_bounds__(256) void k_count(const int* __restrict__ vids,
                                               float* __restrict__ ws) {
  int e = blockIdx.x * 256 + threadIdx.x;
  int* cnt = (int*)(ws + OFF_TF1) + OFFI_CNT;
  atomicAdd(&cnt[vids[e]], 1);
}

__global__ __launch_bounds__(1024) void k_scan(float* __restrict__ ws) {
  int* cnt = (int*)(ws + OFF_TF1) + OFFI_CNT;
  int* cur = (int*)(ws + OFF_TF1) + OFFI_CUR;
  __shared__ int part[1024];
  const int tid = threadIdx.x;
  const int CH = 49;  // 1024*49 >= 50048
  const int base = tid * CH;
  int s = 0;
  for (int j = 0; j < CH; ++j) {
    int idx = base + j;
    if (idx < 50048) s += cnt[idx];
  }
  part[tid] = s;
  __syncthreads();
  int own = s;
  for (int off = 1; off < 1024; off <<= 1) {
    int v = 0;
    if (tid >= off) v = part[tid - off];
    __syncthreads();
    part[tid] += v;
    __syncthreads();
  }
  int run = part[tid] - own;  // exclusive prefix
  for (int j = 0; j < CH; ++j) {
    int idx = base + j;
    if (idx < 50048) {
      cur[idx] = run;
      run += cnt[idx];
    }
  }
}

__global__ __launch_bounds__(256) void k_place(const int* __restrict__ vids,
                                               float* __restrict__ ws) {
  int e = blockIdx.x * 256 + threadIdx.x;
  int* cur = (int*)(ws + OFF_TF1) + OFFI_CUR;
  int* perm = (int*)(ws + OFF_TF1) + OFFI_PERM;
  int* svid = (int*)(ws + OFF_TF1) + OFFI_SVID;
  int v = vids[e];
  int slot = atomicAdd(&cur[v], 1);
  perm[slot] = e;
  svid[slot] = v;
}

// ---------------- k_xstats: Gram(x) 48x48 (row 34 = ones) ----------------
__global__ __launch_bounds__(256) void k_xstats(const float* __restrict__ chem,
                                                float* __restrict__ ws) {
  __shared__ __align__(16) ushort_t xT[2][48 * 72];
  const int t = threadIdx.x, wv = t >> 6, ln = t & 63, r15 = ln & 15, qd = ln >> 4;
  for (int i = t; i < 2 * 14 * 72; i += 256) {
    int b = i / (14 * 72), j = i % (14 * 72);
    int rr = j / 72, e = j % 72;
    xT[b][(34 + rr) * 72 + e] = (rr == 0 && e < 64) ? f2bf(1.0f) : (ushort_t)0;
  }
  float4v g0 = {0, 0, 0, 0}, g1 = {0, 0, 0, 0};
#pragma unroll 2
  for (int it = 0; it < 10; ++it) {
    const int st = blockIdx.x * 10 + it;
    const int buf = it & 1;
    for (int i = t; i < 64 * 34; i += 256) {
      int e = i / 34, k = i - e * 34;
      xT[buf][k * 72 + e] = f2bf(chem[st * 2176 + i]);
    }
    __syncthreads();
    const ushort_t* xb = &xT[buf][0];
#pragma unroll
    for (int ks = 0; ks < 2; ++ks) {
      const ushort_t* xk = xb + ks * 32 + 8 * qd;
      short8 f0 = *(const short8*)&xk[(0 + r15) * 72];
      short8 f1 = *(const short8*)&xk[(16 + r15) * 72];
      short8 f2v = *(const short8*)&xk[(32 + r15) * 72];
      if (wv == 0) { g0 = MFMA16(f0, f0, g0); g1 = MFMA16(f0, f1, g1); }
      else if (wv == 1) { g0 = MFMA16(f0, f2v, g0); g1 = MFMA16(f1, f1, g1); }
      else if (wv == 2) { g0 = MFMA16(f1, f2v, g0); }
      else { g0 = MFMA16(f2v, f2v, g0); }
    }
  }
  float* GX = ws + OFF_GX;
  int ti0, tj0, ti1 = -1, tj1 = -1;
  if (wv == 0) { ti0 = 0; tj0 = 0; ti1 = 0; tj1 = 1; }
  else if (wv == 1) { ti0 = 0; tj0 = 2; ti1 = 1; tj1 = 1; }
  else if (wv == 2) { ti0 = 1; tj0 = 2; }
  else { ti0 = 2; tj0 = 2; }
#pragma unroll
  for (int r = 0; r < 4; ++r)
    atomicAdd(&GX[(16 * ti0 + 4 * qd + r) * 48 + 16 * tj0 + r15], g0[r]);
  if (ti1 >= 0)
#pragma unroll
    for (int r = 0; r < 4; ++r)
      atomicAdd(&GX[(16 * ti1 + 4 * qd + r) * 48 + 16 * tj1 + r15], g1[r]);
}

// ---------------- k_bn1: BN1 affine from Gram(x) ----------------
__global__ __launch_bounds__(64) void k_bn1(const float* __restrict__ b1,
                                            const float* __restrict__ g1,
                                            const float* __restrict__ be1,
                                            float* __restrict__ ws) {
  const int c = blockIdx.x, i = threadIdx.x;
  __shared__ float wc[34];
  const ushort_t* w1t = (const ushort_t*)(ws + OFF_W1T);
  const float* GX = ws + OFF_GX;
  if (i < 34) wc[i] = bf2f(w1t[c * 64 + i]);
  __syncthreads();
  float p = 0.0f, ps = 0.0f;
  if (i < 34) {
    float gi = 0.0f;
    for (int j = 0; j < 34; ++j) {
      int a = i, b = j;
      if ((a >> 4) > (b >> 4)) { int tt = a; a = b; b = tt; }
      gi += GX[a * 48 + b] * wc[j];
    }
    p = wc[i] * gi;
    ps = wc[i] * GX[i * 48 + 34];
  }
#pragma unroll
  for (int off = 1; off < 64; off <<= 1) {
    p += __shfl_xor(p, off);
    ps += __shfl_xor(ps, off);
  }
  if (i == 0) {
    const float E = (float)E_EDGES;
    float bc = b1[c];
    float sum = ps + E * bc;
    float sq = p + 2.0f * bc * ps + E * bc * bc;
    float m = sum / E, v = sq / E - m * m;
    float a = g1[c] * rsqrtf(v + BN_EPS);
    ws[OFF_A1 + c] = a;
    ws[OFF_C1 + c] = a * (bc - m) + be1[c];
  }
}

// ---------------- k_ggram: Gram(geom) 48x48 + ones row 48 (over N nodes) ----------------
__global__ __launch_bounds__(256) void k_ggram(const float* __restrict__ geom,
                                               float* __restrict__ ws) {
  __shared__ __align__(16) ushort_t xT[2][64 * 72];
  const int t = threadIdx.x, wv = t >> 6, ln = t & 63, r15 = ln & 15, qd = ln >> 4;
  for (int i = t; i < 2 * 15 * 72; i += 256) {  // zero rows 49..63 both buffers
    int b = i / (15 * 72), j = i % (15 * 72);
    xT[b][(49 + j / 72) * 72 + (j % 72)] = 0;
  }
  float4v g0 = {0, 0, 0, 0}, g1 = {0, 0, 0, 0}, g2 = {0, 0, 0, 0};
  for (int it = 0; it < 10; ++it) {
    const int st = blockIdx.x * 10 + it;
    if (st >= 782) break;
    const int buf = it & 1;
    const int nb = st * 64;
    for (int i = t; i < 64 * 48; i += 256) {
      int nl = i / 48, k = i - nl * 48;
      int n = nb + nl;
      xT[buf][k * 72 + nl] = (n < N_NODES) ? f2bf(geom[n * 48 + k]) : (ushort_t)0;
    }
    if (t < 64) xT[buf][48 * 72 + t] = (nb + t < N_NODES) ? f2bf(1.0f) : (ushort_t)0;
    __syncthreads();
    const ushort_t* xb = &xT[buf][0];
#pragma unroll
    for (int ks = 0; ks < 2; ++ks) {
      const ushort_t* xk = xb + ks * 32 + 8 * qd;
      short8 f0 = *(const short8*)&xk[(0 + r15) * 72];
      short8 f1 = *(const short8*)&xk[(16 + r15) * 72];
      short8 f2v = *(const short8*)&xk[(32 + r15) * 72];
      short8 f3 = *(const short8*)&xk[(48 + r15) * 72];
      if (wv == 0) { g0 = MFMA16(f0, f0, g0); g1 = MFMA16(f0, f1, g1); g2 = MFMA16(f0, f2v, g2); }
      else if (wv == 1) { g0 = MFMA16(f0, f3, g0); g1 = MFMA16(f1, f1, g1); g2 = MFMA16(f1, f2v, g2); }
      else if (wv == 2) { g0 = MFMA16(f1, f3, g0); g1 = MFMA16(f2v, f2v, g1); g2 = MFMA16(f2v, f3, g2); }
      else { g0 = MFMA16(f3, f3, g0); }
    }
  }
  float* GG = ws + OFF_GG;
  int ti[3], tj[3], nacc;
  if (wv == 0) { ti[0]=0; tj[0]=0; ti[1]=0; tj[1]=1; ti[2]=0; tj[2]=2; nacc=3; }
  else if (wv == 1) { ti[0]=0; tj[0]=3; ti[1]=1; tj[1]=1; ti[2]=1; tj[2]=2; nacc=3; }
  else if (wv == 2) { ti[0]=1; tj[0]=3; ti[1]=2; tj[1]=2; ti[2]=2; tj[2]=3; nacc=3; }
  else { ti[0]=3; tj[0]=3; nacc=1; }
  float4v gs[3] = {g0, g1, g2};
  for (int s = 0; s < nacc; ++s)
#pragma unroll
    for (int r = 0; r < 4; ++r)
      atomicAdd(&GG[(16 * ti[s] + 4 * qd + r) * 64 + 16 * tj[s] + r15], gs[s][r]);
}

// ---------------- k_gbn1: geom BN1 affine from Gram(geom) ----------------
__global__ __launch_bounds__(64) void k_gbn1(const float* __restrict__ wg1,
                                             const float* __restrict__ bg1,
                                             const float* __restrict__ gg1,
                                             const float* __restrict__ beg1,
                                             float* __restrict__ ws) {
  const int c = blockIdx.x, i = threadIdx.x;
  __shared__ float wc[48];
  const float* GG = ws + OFF_GG;
  if (i < 48) wc[i] = wg1[i * 64 + c];
  __syncthreads();
  float p = 0.0f, ps = 0.0f;
  if (i < 48) {
    float gi = 0.0f;
    for (int j = 0; j < 48; ++j) {
      int a = i, b = j;
      if ((a >> 4) > (b >> 4)) { int tt = a; a = b; b = tt; }
      gi += GG[a * 64 + b] * wc[j];
    }
    p = wc[i] * gi;
    ps = wc[i] * GG[i * 64 + 48];
  }
#pragma unroll
  for (int off = 1; off < 64; off <<= 1) {
    p += __shfl_xor(p, off);
    ps += __shfl_xor(ps, off);
  }
  if (i == 0) {
    const float Nf = (float)N_NODES;
    float bc = bg1[c];
    float sum = ps + Nf * bc;
    float sq = p + 2.0f * bc * ps + Nf * bc * bc;
    float m = sum / Nf, v = sq / Nf - m * m;
    float a = gg1[c] * rsqrtf(v + BN_EPS);
    ws[OFF_GA1 + c] = a;
    ws[OFF_GC1 + c] = beg1[c] - a * m;  // applied to tg1 (incl bias)
  }
}

// ---------------- Gram(h) helpers ----------------
template <int TJA, int TJB>  // TJA < TJB
__device__ __forceinline__ void ghstep(const ushort_t* hk, int r15, float4v (&g)[11]) {
  short8 f[TJB + 1];
#pragma unroll
  for (int i = 0; i <= TJB; ++i) f[i] = *(const short8*)&hk[(16 * i + r15) * 72];
  short8 f8 = *(const short8*)&hk[(128 + r15) * 72];
  int s = 0;
#pragma unroll
  for (int ti = 0; ti <= TJA; ++ti) { g[s] = MFMA16(f[ti], f[TJA], g[s]); ++s; }
  g[s] = MFMA16(f8, f[TJA], g[s]); ++s;
#pragma unroll
  for (int ti = 0; ti <= TJB; ++ti) { g[s] = MFMA16(f[ti], f[TJB], g[s]); ++s; }
  g[s] = MFMA16(f8, f[TJB], g[s]);
}

__device__ __forceinline__ void ghtile(float* GH, int ti, int tj, int r15, int qd,
                                       const float4v v) {
#pragma unroll
  for (int r = 0; r < 4; ++r)
    atomicAdd(&GH[(16 * ti + 4 * qd + r) * 144 + 16 * tj + r15], v[r]);
}

template <int TJA, int TJB>
__device__ __forceinline__ void ghflush(float* GH, int r15, int qd, const float4v (&g)[11]) {
  int s = 0;
#pragma unroll
  for (int ti = 0; ti <= TJA; ++ti) { ghtile(GH, ti, TJA, r15, qd, g[s]); ++s; }
  ghtile(GH, 8, TJA, r15, qd, g[s]); ++s;
#pragma unroll
  for (int ti = 0; ti <= TJB; ++ti) { ghtile(GH, ti, TJB, r15, qd, g[s]); ++s; }
  ghtile(GH, 8, TJB, r15, qd, g[s]);
}

// ---------------- k_h: stage A + Gram(h) ----------------
__global__ __launch_bounds__(256) void k_h(const float* __restrict__ chem,
                                           float* __restrict__ ws) {
  __shared__ __align__(16) ushort_t hT[2][144 * 72];
  const int t = threadIdx.x, wv = t >> 6, ln = t & 63, r15 = ln & 15, qd = ln >> 4;
  const ushort_t* w1t = (const ushort_t*)(ws + OFF_W1T);
  for (int i = t; i < 2 * 16 * 72; i += 256) {
    int b = i / (16 * 72), j = i % (16 * 72);
    int rr = j / 72, e = j % 72;
    hT[b][(128 + rr) * 72 + e] = (rr == 0 && e < 64) ? f2bf(1.0f) : (ushort_t)0;
  }
  float a1c[2], c1c[2];
#pragma unroll
  for (int cf = 0; cf < 2; ++cf) {
    int col = 32 * wv + 16 * cf + r15;
    a1c[cf] = ws[OFF_A1 + col];
    c1c[cf] = ws[OFF_C1 + col];
  }
  float4v gacc[11];
#pragma unroll
  for (int s = 0; s < 11; ++s) gacc[s] = (float4v){0, 0, 0, 0};

#pragma unroll 2
  for (int it = 0; it < 10; ++it) {
    const int st = blockIdx.x * 10 + it;
    const int buf = it & 1;
    const int e_base = st * 64;
    short8 xa0[4], xa1[4];
#pragma unroll
    for (int rb = 0; rb < 4; ++rb)
      load_xfrag(chem, e_base + 16 * rb + r15, qd, &xa0[rb], &xa1[rb]);
#pragma unroll
    for (int cf = 0; cf < 2; ++cf) {
      const int col = 32 * wv + 16 * cf + r15;
      short8 wb0 = *(const short8*)&w1t[col * 64 + 8 * qd];
      short8 wb1 = *(const short8*)&w1t[col * 64 + 32 + 8 * qd];
#pragma unroll
      for (int rb = 0; rb < 4; ++rb) {
        float4v acc = (float4v){0, 0, 0, 0};
        acc = MFMA16(xa0[rb], wb0, acc);
        acc = MFMA16(xa1[rb], wb1, acc);
        ull_t pk = 0;
#pragma unroll
        for (int r = 0; r < 4; ++r) {
          float hv = silu_(fmaf(a1c[cf], acc[r], c1c[cf]));
          pk |= ((ull_t)f2bf(hv)) << (16 * r);
        }
        *(ull_t*)&hT[buf][col * 72 + 16 * rb + 4 * qd] = pk;
      }
    }
    __syncthreads();
    const ushort_t* hb = &hT[buf][0];
#pragma unroll
    for (int ks = 0; ks < 2; ++ks) {
      const ushort_t* hk = hb + ks * 32 + 8 * qd;
      if (wv == 0) ghstep<0, 7>(hk, r15, gacc);
      else if (wv == 1) ghstep<1, 6>(hk, r15, gacc);
      else if (wv == 2) ghstep<2, 5>(hk, r15, gacc);
      else ghstep<3, 4>(hk, r15, gacc);
    }
  }
  float* GH = ws + OFF_GH;
  if (wv == 0) ghflush<0, 7>(GH, r15, qd, gacc);
  else if (wv == 1) ghflush<1, 6>(GH, r15, qd, gacc);
  else if (wv == 2) ghflush<2, 5>(GH, r15, qd, gacc);
  else ghflush<3, 4>(GH, r15, qd, gacc);
}

// ---------------- k_bn2: BN2 affine from Gram(h) ----------------
__global__ __launch_bounds__(128) void k_bn2(const float* __restrict__ b2,
                                             const float* __restrict__ g2,
                                             const float* __restrict__ be2,
                                             float* __restrict__ ws) {
  const int c = blockIdx.x, i = threadIdx.x;
  __shared__ float wcol[128];
  __shared__ float redQ[2], redS[2];
  const ushort_t* w2t = (const ushort_t*)(ws + OFF_W2T);
  const float* GH = ws + OFF_GH;
  wcol[i] = bf2f(w2t[c * 128 + i]);
  __syncthreads();
  float wi = wcol[i];
  float gi = 0.0f;
  for (int j = 0; j < 128; ++j) {
    int a = i, b = j;
    if ((a >> 4) > (b >> 4)) { int tt = a; a = b; b = tt; }
    gi += GH[a * 144 + b] * wcol[j];
  }
  float p = wi * gi;
  float ps = wi * GH[128 * 144 + i];
#pragma unroll
  for (int off = 1; off < 64; off <<= 1) {
    p += __shfl_xor(p, off);
    ps += __shfl_xor(ps, off);
  }
  const int wv = i >> 6, ln = i & 63;
  if (ln == 0) { redQ[wv] = p; redS[wv] = ps; }
  __syncthreads();
  if (i == 0) {
    float q = redQ[0] + redQ[1], s = redS[0] + redS[1];
    const float E = (float)E_EDGES;
    float bc = b2[c];
    float sum = s + E * bc;
    float sq = q + 2.0f * bc * s + E * bc * bc;
    float m = sum / E, v = sq / E - m * m;
    float a = g2[c] * rsqrtf(v + BN_EPS);
    ws[OFF_A2 + c] = a;
    ws[OFF_C2 + c] = a * (bc - m) + be2[c];
  }
}

// ---------------- k_scatter: sorted edges, stage A + B + gate + run-merged scatter ----------
__global__ __launch_bounds__(256) void k_scatter(const float* __restrict__ chem,
                                                 float* __restrict__ ws) {
  __shared__ __align__(16) ushort_t hS[2][64 * 136];
  const int t = threadIdx.x, wv = t >> 6, ln = t & 63, r15 = ln & 15, qd = ln >> 4;
  const ushort_t* w1t = (const ushort_t*)(ws + OFF_W1T);
  const ushort_t* w2t = (const ushort_t*)(ws + OFF_W2T);
  const int* perm = (const int*)(ws + OFF_TF1) + OFFI_PERM;
  const int* svid = (const int*)(ws + OFF_TF1) + OFFI_SVID;
  float* node = ws + OFF_NODE;
  float a1c[2], c1c[2], aF2[2], cF2[2], aC2[2], cC2[2];
#pragma unroll
  for (int cf = 0; cf < 2; ++cf) {
    int col = 32 * wv + 16 * cf + r15;
    a1c[cf] = ws[OFF_A1 + col];
    c1c[cf] = ws[OFF_C1 + col];
    aF2[cf] = ws[OFF_A2 + col];
    cF2[cf] = ws[OFF_C2 + col];
    aC2[cf] = ws[OFF_A2 + 128 + col];
    cC2[cf] = ws[OFF_C2 + 128 + col];
  }
  for (int it = 0; it < 4; ++it) {
    const int st = blockIdx.x * 4 + it;
    const int buf = it & 1;
    const int s_base = st * 64;
    int pr[4];
    int4 vv[4];
#pragma unroll
    for (int rb = 0; rb < 4; ++rb) {
      pr[rb] = perm[s_base + 16 * rb + r15];
      vv[rb] = *(const int4*)&svid[s_base + 16 * rb + 4 * qd];
    }
    short8 xa0[4], xa1[4];
#pragma unroll
    for (int rb = 0; rb < 4; ++rb) load_xfrag(chem, pr[rb], qd, &xa0[rb], &xa1[rb]);
#pragma unroll
    for (int cf = 0; cf < 2; ++cf) {
      const int col = 32 * wv + 16 * cf + r15;
      short8 wb0 = *(const short8*)&w1t[col * 64 + 8 * qd];
      short8 wb1 = *(const short8*)&w1t[col * 64 + 32 + 8 * qd];
#pragma unroll
      for (int rb = 0; rb < 4; ++rb) {
        float4v acc = (float4v){0, 0, 0, 0};
        acc = MFMA16(xa0[rb], wb0, acc);
        acc = MFMA16(xa1[rb], wb1, acc);
#pragma unroll
        for (int r = 0; r < 4; ++r) {
          float hv = silu_(fmaf(a1c[cf], acc[r], c1c[cf]));
          hS[buf][(16 * rb + 4 * qd + r) * 136 + col] = f2bf(hv);
        }
      }
    }
    __syncthreads();
    const ushort_t* hb = &hS[buf][0];
#pragma unroll
    for (int cf = 0; cf < 2; ++cf) {
      const int colF = 32 * wv + 16 * cf + r15;
      float4v accF[4], accC[4];
#pragma unroll
      for (int rb = 0; rb < 4; ++rb) {
        accF[rb] = (float4v){0, 0, 0, 0};
        accC[rb] = (float4v){0, 0, 0, 0};
      }
#pragma unroll
      for (int ks = 0; ks < 4; ++ks) {
        short8 bF = *(const short8*)&w2t[colF * 128 + ks * 32 + 8 * qd];
        short8 bC = *(const short8*)&w2t[(128 + colF) * 128 + ks * 32 + 8 * qd];
#pragma unroll
        for (int rb = 0; rb < 4; ++rb) {
          short8 hf = *(const short8*)&hb[(16 * rb + r15) * 136 + ks * 32 + 8 * qd];
          accF[rb] = MFMA16(hf, bF, accF[rb]);
          accC[rb] = MFMA16(hf, bC, accC[rb]);
        }
      }
#pragma unroll
      for (int rb = 0; rb < 4; ++rb) {
        float gv[4];
#pragma unroll
        for (int r = 0; r < 4; ++r) {
          float F = fmaf(aF2[cf], accF[rb][r], cF2[cf]);
          float Co = fmaf(aC2[cf], accC[rb][r], cC2[cf]);
          gv[r] = sigmoid_(F) * softplus_(Co);
        }
        // slots 16rb+4qd+0..3 are consecutive & sorted by vid: merge runs
        int cv = vv[rb].x;
        float s = gv[0];
        if (vv[rb].y == cv) s += gv[1];
        else { atomicAdd(node + (size_t)cv * 128 + colF, s); cv = vv[rb].y; s = gv[1]; }
        if (vv[rb].z == cv) s += gv[2];
        else { atomicAdd(node + (size_t)cv * 128 + colF, s); cv = vv[rb].z; s = gv[2]; }
        if (vv[rb].w == cv) s += gv[3];
        else { atomicAdd(node + (size_t)cv * 128 + colF, s); cv = vv[rb].w; s = gv[3]; }
        atomicAdd(node + (size_t)cv * 128 + colF, s);
      }
    }
  }
}

// ---------------- k_geom_main: tg1 -> BN1(silu) -> tg2 (+GS2 stats) ----------------
__global__ __launch_bounds__(256) void k_geom_main(
    const float* __restrict__ geom, const float* __restrict__ wg1,
    const float* __restrict__ bg1, const float* __restrict__ wg2,
    const float* __restrict__ bg2, float* __restrict__ ws) {
  __shared__ float ssum[64], ssq[64];
  const int t = threadIdx.x, lane = t & 63, w = t >> 6;
  if (t < 64) { ssum[t] = 0.0f; ssq[t] = 0.0f; }
  const float a1 = ws[OFF_GA1 + lane], c1 = ws[OFF_GC1 + lane];
  const float bcol = bg1[lane], b2col = bg2[lane];
  __syncthreads();
  const int nb = blockIdx.x * 16 + w * 4;
  float x[4], tg1[4], hg[4], acc[4];
#pragma unroll
  for (int u = 0; u < 4; u++) {
    x[u] = (lane < 48) ? geom[(nb + u) * 48 + lane] : 0.0f;
    tg1[u] = bcol;
  }
#pragma unroll 16
  for (int k = 0; k < 48; k++) {
    float wvv = wg1[k * 64 + lane];
#pragma unroll
    for (int u = 0; u < 4; u++) tg1[u] = fmaf(__shfl(x[u], k), wvv, tg1[u]);
  }
#pragma unroll
  for (int u = 0; u < 4; u++) {
    hg[u] = silu_(fmaf(a1, tg1[u], c1));
    acc[u] = b2col;
  }
#pragma unroll 16
  for (int k = 0; k < 64; k++) {
    float wvv = wg2[k * 64 + lane];
#pragma unroll
    for (int u = 0; u < 4; u++) acc[u] = fmaf(__shfl(hg[u], k), wvv, acc[u]);
  }
  float bs = 0.0f, bq = 0.0f;
#pragma unroll
  for (int u = 0; u < 4; u++) {
    ws[OFF_TG2 + (nb + u) * 64 + lane] = acc[u];
    bs += acc[u]; bq += acc[u] * acc[u];
  }
  atomicAdd(&ssum[lane], bs);
  atomicAdd(&ssq[lane], bq);
  __syncthreads();
  if (t < 64) {
    atomicAdd(ws + OFF_GS2SUM + t, ssum[t]);
    atomicAdd(ws + OFF_GS2SQ + t, ssq[t]);
  }
}

// ---------------- k_fuse1: MFMA z[192] @ wf1 -> tf1 raw + FS1 stats ----------------
__global__ __launch_bounds__(256) void k_fuse1(const float* __restrict__ bf1,
                                               const float* __restrict__ gg2,
                                               const float* __restrict__ beg2,
                                               float* __restrict__ ws) {
  __shared__ __align__(16) ushort_t zS[64 * 200];
  __shared__ float agS[64], cgS[64];
  const int t = threadIdx.x, wv = t >> 6, ln = t & 63, r15 = ln & 15, qd = ln >> 4;
  const int nb = blockIdx.x * 64;
  const float invN = 1.0f / (float)N_NODES;
  if (t < 64) {
    float s = ws[OFF_GS2SUM + t], q = ws[OFF_GS2SQ + t];
    float m = s * invN, v = q * invN - m * m;
    float a = gg2[t] * rsqrtf(v + BN_EPS);
    agS[t] = a;
    cgS[t] = beg2[t] - a * m;
  }
  __syncthreads();
  const float* node = ws + OFF_NODE;
  const float* tg2 = ws + OFF_TG2;
  for (int i = t; i < 64 * 32; i += 256) {  // chem part: cols 0..127
    int row = i >> 5, c4 = (i & 31) << 2, n = nb + row;
    float4 v = (n < N_NODES) ? *(const float4*)&node[n * 128 + c4] : make_float4(0, 0, 0, 0);
    *(ull_t*)&zS[row * 200 + c4] = pack4(v.x, v.y, v.z, v.w);
  }
  for (int i = t; i < 64 * 16; i += 256) {  // geom part: cols 128..191 (BN applied)
    int row = i >> 4, c4 = (i & 15) << 2, n = nb + row;
    float4 v = (n < N_NODES) ? *(const float4*)&tg2[n * 64 + c4] : make_float4(0, 0, 0, 0);
    float z0 = fmaf(agS[c4 + 0], v.x, cgS[c4 + 0]);
    float z1 = fmaf(agS[c4 + 1], v.y, cgS[c4 + 1]);
    float z2 = fmaf(agS[c4 + 2], v.z, cgS[c4 + 2]);
    float z3 = fmaf(agS[c4 + 3], v.w, cgS[c4 + 3]);
    *(ull_t*)&zS[row * 200 + 128 + c4] = pack4(z0, z1, z2, z3);
  }
  __syncthreads();
  const ushort_t* wt = (const ushort_t*)(ws + OFF_WF1T);
#pragma unroll
  for (int cf = 0; cf < 2; ++cf) {
    const int col = 32 * wv + 16 * cf + r15;
    float4v acc[4];
#pragma unroll
    for (int rb = 0; rb < 4; ++rb) acc[rb] = (float4v){0, 0, 0, 0};
#pragma unroll
    for (int ks = 0; ks < 6; ++ks) {
      short8 bfrag = *(const short8*)&wt[col * 192 + ks * 32 + 8 * qd];
#pragma unroll
      for (int rb = 0; rb < 4; ++rb) {
        short8 afrag = *(const short8*)&zS[(16 * rb + r15) * 200 + ks * 32 + 8 * qd];
        acc[rb] = MFMA16(afrag, bfrag, acc[rb]);
      }
    }
    const float bcol = bf1[col];
    float s = 0.0f, q = 0.0f;
#pragma unroll
    for (int rb = 0; rb < 4; ++rb)
#pragma unroll
      for (int r = 0; r < 4; ++r) {
        int n = nb + 16 * rb + 4 * qd + r;
        float raw = acc[rb][r] + bcol;
        if (n < N_NODES) {
          ws[OFF_TF1 + (size_t)n * 128 + col] = raw;
          s += raw;
          q += raw * raw;
        }
      }
    s += __shfl_xor(s, 16); q += __shfl_xor(q, 16);
    s += __shfl_xor(s, 32); q += __shfl_xor(q, 32);
    if (ln < 16) {
      atomicAdd(ws + OFF_FS1SUM + col, s);
      atomicAdd(ws + OFF_FS1SQ + col, q);
    }
  }
}

// ---------------- k_fuse2: MFMA silu(bn(tf1)) @ wf2 -> tf2 raw + FS2 stats ----------------
__global__ __launch_bounds__(256) void k_fuse2(const float* __restrict__ bf2,
                                               const float* __restrict__ gf1,
                                               const float* __restrict__ bef1,
                                               float* __restrict__ ws) {
  __shared__ __align__(16) ushort_t zS[64 * 136];
  __shared__ float aS[128], cS[128];
  const int t = threadIdx.x, wv = t >> 6, ln = t & 63, r15 = ln & 15, qd = ln >> 4;
  const int nb = blockIdx.x * 64;
  const float invN = 1.0f / (float)N_NODES;
  if (t < 128) {
    float s = ws[OFF_FS1SUM + t], q = ws[OFF_FS1SQ + t];
    float m = s * invN, v = q * invN - m * m;
    float a = gf1[t] * rsqrtf(v + BN_EPS);
    aS[t] = a;
    cS[t] = bef1[t] - a * m;
  }
  __syncthreads();
  const float* tf1 = ws + OFF_TF1;
  for (int i = t; i < 64 * 32; i += 256) {
    int row = i >> 5, c4 = (i & 31) << 2, n = nb + row;
    float4 v = (n < N_NODES) ? *(const float4*)&tf1[(size_t)n * 128 + c4] : make_float4(0, 0, 0, 0);
    float z0 = silu_(fmaf(aS[c4 + 0], v.x, cS[c4 + 0]));
    float z1 = silu_(fmaf(aS[c4 + 1], v.y, cS[c4 + 1]));
    float z2 = silu_(fmaf(aS[c4 + 2], v.z, cS[c4 + 2]));
    float z3 = silu_(fmaf(aS[c4 + 3], v.w, cS[c4 + 3]));
    *(ull_t*)&zS[row * 136 + c4] = pack4(z0, z1, z2, z3);
  }
  __syncthreads();
  const ushort_t* wt = (const ushort_t*)(ws + OFF_WF2T);
#pragma unroll
  for (int cf = 0; cf < 2; ++cf) {
    const int col = 32 * wv + 16 * cf + r15;
    float4v acc[4];
#pragma unroll
    for (int rb = 0; rb < 4; ++rb) acc[rb] = (float4v){0, 0, 0, 0};
#pragma unroll
    for (int ks = 0; ks < 4; ++ks) {
      short8 bfrag = *(const short8*)&wt[col * 128 + ks * 32 + 8 * qd];
#pragma unroll
      for (int rb = 0; rb < 4; ++rb) {
        short8 afrag = *(const short8*)&zS[(16 * rb + r15) * 136 + ks * 32 + 8 * qd];
        acc[rb] = MFMA16(afrag, bfrag, acc[rb]);
      }
    }
    const float bcol = bf2[col];
    float s = 0.0f, q = 0.0f;
#pragma unroll
    for (int rb = 0; rb < 4; ++rb)
#pragma unroll
      for (int r = 0; r < 4; ++r) {
        int n = nb + 16 * rb + 4 * qd + r;
        float raw = acc[rb][r] + bcol;
        if (n < N_NODES) {
          ws[OFF_TF2 + (size_t)n * 128 + col] = raw;
          s += raw;
          q += raw * raw;
        }
      }
    s += __shfl_xor(s, 16); q += __shfl_xor(q, 16);
    s += __shfl_xor(s, 32); q += __shfl_xor(q, 32);
    if (ln < 16) {
      atomicAdd(ws + OFF_FS2SUM + col, s);
      atomicAdd(ws + OFF_FS2SQ + col, q);
    }
  }
}

__global__ __launch_bounds__(256) void k_final(const float* __restrict__ gf2,
                                               const float* __restrict__ bef2,
                                               const float* __restrict__ ws,
                                               float* __restrict__ out) {
  const int idx = blockIdx.x * 256 + threadIdx.x;
  const int base = idx * 4;
  if (base >= N_NODES * 128) return;
  const float invN = 1.0f / (float)N_NODES;
  const int c0 = base & 127;
  float4 v = *(const float4*)(ws + OFF_TF2 + base);
  float vv[4] = {v.x, v.y, v.z, v.w}, r[4];
#pragma unroll
  for (int j = 0; j < 4; j++) {
    int c = c0 + j;
    float s = ws[OFF_FS2SUM + c], q = ws[OFF_FS2SQ + c];
    float m = s * invN, var = q * invN - m * m;
    float a = gf2[c] * rsqrtf(var + BN_EPS);
    r[j] = fmaf(a, vv[j] - m, bef2[c]);
  }
  *(float4*)(out + base) = make_float4(r[0], r[1], r[2], r[3]);
}

extern "C" void kernel_launch(void* const* d_in, const int* in_sizes, int n_in,
                              void* d_out, int out_size, void* d_ws, size_t ws_size,
                              hipStream_t stream) {
  const float* chem = (const float*)d_in[0];
  const float* geom = (const float*)d_in[1];
  const int* vids = (const int*)d_in[2];
  const float* w_c1 = (const float*)d_in[3];  const float* b_c1 = (const float*)d_in[4];
  const float* g_c1 = (const float*)d_in[5];  const float* be_c1 = (const float*)d_in[6];
  const float* w_c2 = (const float*)d_in[7];  const float* b_c2 = (const float*)d_in[8];
  const float* g_c2 = (const float*)d_in[9];  const float* be_c2 = (const float*)d_in[10];
  const float* w_g1 = (const float*)d_in[11]; const float* b_g1 = (const float*)d_in[12];
  const float* g_g1 = (const float*)d_in[13]; const float* be_g1 = (const float*)d_in[14];
  const float* w_g2 = (const float*)d_in[15]; const float* b_g2 = (const float*)d_in[16];
  const float* g_g2 = (const float*)d_in[17]; const float* be_g2 = (const float*)d_in[18];
  const float* w_f1 = (const float*)d_in[19]; const float* b_f1 = (const float*)d_in[20];
  const float* g_f1 = (const float*)d_in[21]; const float* be_f1 = (const float*)d_in[22];
  const float* w_f2 = (const float*)d_in[23]; const float* b_f2 = (const float*)d_in[24];
  const float* g_f2 = (const float*)d_in[25]; const float* be_f2 = (const float*)d_in[26];
  float* ws = (float*)d_ws;
  float* out = (float*)d_out;

  // zero Grams + stats + node accumulator, and the sort counter region
  hipMemsetAsync(d_ws, 0, (size_t)OFF_TG2 * sizeof(float), stream);
  hipMemsetAsync((char*)d_ws + (size_t)OFF_TF1 * sizeof(float), 0, 50048 * sizeof(int), stream);

  k_prep<<<dim3(320), dim3(256), 0, stream>>>(w_c1, w_c2, w_f1, w_f2, ws);
  k_count<<<dim3(3125), dim3(256), 0, stream>>>(vids, ws);
  k_scan<<<dim3(1), dim3(1024), 0, stream>>>(ws);
  k_place<<<dim3(3125), dim3(256), 0, stream>>>(vids, ws);
  k_xstats<<<dim3(1250), dim3(256), 0, stream>>>(chem, ws);
  k_bn1<<<dim3(128), dim3(64), 0, stream>>>(b_c1, g_c1, be_c1, ws);
  k_ggram<<<dim3(79), dim3(256), 0, stream>>>(geom, ws);
  k_gbn1<<<dim3(64), dim3(64), 0, stream>>>(w_g1, b_g1, g_g1, be_g1, ws);
  k_h<<<dim3(1250), dim3(256), 0, stream>>>(chem, ws);
  k_bn2<<<dim3(256), dim3(128), 0, stream>>>(b_c2, g_c2, be_c2, ws);
  k_scatter<<<dim3(3125), dim3(256), 0, stream>>>(chem, ws);
  k_geom_main<<<dim3(3125), dim3(256), 0, stream>>>(geom, w_g1, b_g1, w_g2, b_g2, ws);
  k_fuse1<<<dim3(782), dim3(256), 0, stream>>>(b_f1, g_g2, be_g2, ws);
  k_fuse2<<<dim3(782), dim3(256), 0, stream>>>(b_f2, g_f1, be_f1, ws);
  k_final<<<dim3(6250), dim3(256), 0, stream>>>(g_f2, be_f2, ws, out);
}